// Round 7
// baseline (289.267 us; speedup 1.0000x reference)
//
#include <hip/hip_runtime.h>
#include <hip/hip_fp16.h>
#include <hip/hip_bf16.h>
#include <math.h>

#define L 8192
#define LOG2L 13
#define B 16
#define CIN 64
#define COUT 64
#define KK 64

#define PI_F 3.14159265358979323846f

typedef float v2f __attribute__((ext_vector_type(2)));

// XOR swizzle for the bit-reversal scatter phase: bijective involution,
// spreads the 32-way bank collision of bitrev-scatter into <=2-way.
__device__ __forceinline__ int swz(int n) { return n ^ ((n >> 8) & 31); }

// native sincos: v_sin_f32/v_cos_f32 take revolutions, reduce with fract first
__device__ __forceinline__ void nsincos(float ang, float* sn, float* cs) {
    float r = ang * 0.15915494309189535f;   // 1/(2*pi)
    r = r - floorf(r);
    *sn = __builtin_amdgcn_sinf(r);
    *cs = __builtin_amdgcn_cosf(r);
}

// ---------------- kernel 0: twiddle table W[j] = e^{-i*pi*j/4096}, j in [0,4096) ----------------
__global__ __launch_bounds__(256) void k_twiddle(float2* __restrict__ W) {
    int j = blockIdx.x * 256 + threadIdx.x;
    float ang = -PI_F * (float)j * (1.0f / 4096.0f);
    W[j] = make_float2(cosf(ang), sinf(ang));
}

// ---------------- kernel 1: partial per-batch min/max of |x| ----------------
__global__ __launch_bounds__(256) void k_reduce1(const float* __restrict__ xr,
                                                 const float* __restrict__ xi,
                                                 float* __restrict__ pmin,
                                                 float* __restrict__ pmax) {
    int bid = blockIdx.x;            // 1024 = 16 batches * 64 slices
    int batch = bid >> 6, slice = bid & 63;
    size_t base = (size_t)batch * CIN * L + (size_t)slice * L;
    int tid = threadIdx.x;
    float mn = 3.4e38f, mx = 0.0f;
    for (int r = 0; r < 32; ++r) {
        int idx = r * 256 + tid;
        float a = xr[base + idx], b = xi[base + idx];
        float m = sqrtf(a * a + b * b);
        mn = fminf(mn, m);
        mx = fmaxf(mx, m);
    }
    __shared__ float smn[4], smx[4];
    for (int off = 32; off >= 1; off >>= 1) {
        mn = fminf(mn, __shfl_down(mn, off));
        mx = fmaxf(mx, __shfl_down(mx, off));
    }
    int wave = tid >> 6;
    if ((tid & 63) == 0) { smn[wave] = mn; smx[wave] = mx; }
    __syncthreads();
    if (tid == 0) {
        for (int w = 1; w < 4; ++w) { mn = fminf(mn, smn[w]); mx = fmaxf(mx, smx[w]); }
        pmin[bid] = mn;
        pmax[bid] = mx;
    }
}

// ---------------- kernel 2: final min/max ----------------
__global__ __launch_bounds__(64) void k_reduce2(const float* __restrict__ pmin,
                                                const float* __restrict__ pmax,
                                                float* __restrict__ mmin,
                                                float* __restrict__ mmax) {
    int b = blockIdx.x, t = threadIdx.x;
    float mn = pmin[b * 64 + t], mx = pmax[b * 64 + t];
    for (int off = 32; off >= 1; off >>= 1) {
        mn = fminf(mn, __shfl_down(mn, off));
        mx = fmaxf(mx, __shfl_down(mx, off));
    }
    if (t == 0) { mmin[b] = mn; mmax[b] = mx; }
}

// ---------------- kernel 3: kernel FFT stats (64-pt DFT, mag+phase) ----------------
__global__ __launch_bounds__(64) void k_kstats(const float* __restrict__ kr,
                                               const float* __restrict__ ki,
                                               float* __restrict__ kmag,
                                               float* __restrict__ kph) {
    int row = blockIdx.x;   // o*64 + j  (4096 rows)
    int k = threadIdx.x;    // output frequency 0..63
    __shared__ float sr[64], si[64];
    sr[k] = kr[row * 64 + k];
    si[k] = ki[row * 64 + k];
    __syncthreads();
    float ar = 0.f, ai = 0.f;
    for (int n = 0; n < 64; ++n) {
        int m = (n * k) & 63;                       // exact mod-64 reduction
        float ang = -2.0f * PI_F * (float)m * (1.0f / 64.0f);
        float s, c;
        __sincosf(ang, &s, &c);
        ar += sr[n] * c - si[n] * s;
        ai += sr[n] * s + si[n] * c;
    }
    kmag[row * 64 + k] = sqrtf(ar * ar + ai * ai);
    kph[row * 64 + k] = atan2f(ai, ar);
}

// ---------------- kernel 4: coupling + forward DIF FFT + bitrev permute ----------------
// x_fft written in NATURAL frequency order as half2 into d_out.
// Twiddles from global table (L1-resident 32KB) instead of per-butterfly sincos.
__global__ __launch_bounds__(512) void k_fwd(const float* __restrict__ xr,
                                             const float* __restrict__ xi,
                                             const float* __restrict__ mmin_,
                                             const float* __restrict__ mmax_,
                                             const float2* __restrict__ Wt,
                                             __half2* __restrict__ xfft) {
    __shared__ float sRe[L];
    __shared__ float sIm[L];
    int row = blockIdx.x;          // b*64 + j
    int b = row >> 6;
    int tid = threadIdx.x;
    float mmin = mmin_[b], mmax = mmax_[b];
    float span = mmax - mmin;
    float invden = 1.0f / (span + 1e-10f);
    size_t base = (size_t)row * L;

    for (int rpt = 0; rpt < L / 512; ++rpt) {
        int idx = rpt * 512 + tid;
        float a = xr[base + idx], c = xi[base + idx];
        float m = sqrtf(a * a + c * c);
        float xn = (m - mmin) * invden;
#pragma unroll
        for (int it = 0; it < 5; ++it) xn = 3.8f * xn * (1.0f - xn);
        float mc = xn * span + mmin;
        float scale = (m > 0.0f) ? (mc / m) : 0.0f;
        sRe[idx] = a * scale;
        sIm[idx] = c * scale;
    }

    // radix-2 DIF, natural in -> bit-reversed out; tw = W[j<<s] = e^{-i pi j/len}
    for (int s = 0; s < LOG2L; ++s) {
        int lg = LOG2L - 1 - s;
        int len = 1 << lg;
        __syncthreads();
        for (int rpt = 0; rpt < (L / 2) / 512; ++rpt) {
            int t = rpt * 512 + tid;
            int j = t & (len - 1);
            int idx = ((t >> lg) << (lg + 1)) | j;
            float ar = sRe[idx], ai = sIm[idx];
            float br = sRe[idx + len], bi = sIm[idx + len];
            sRe[idx] = ar + br;
            sIm[idx] = ai + bi;
            float dr = ar - br, di = ai - bi;
            float2 tw = Wt[j << s];
            sRe[idx + len] = dr * tw.x - di * tw.y;
            sIm[idx + len] = dr * tw.y + di * tw.x;
        }
    }
    __syncthreads();

    // in-LDS bit-reversal permute (swizzled scatter; bijective, race-free)
    float vr[16], vi[16];
#pragma unroll
    for (int r = 0; r < 16; ++r) {
        int idx = r * 512 + tid;
        vr[r] = sRe[idx]; vi[r] = sIm[idx];
    }
    __syncthreads();
#pragma unroll
    for (int r = 0; r < 16; ++r) {
        int idx = r * 512 + tid;
        int n = (int)(__brev((unsigned)idx) >> 19);   // target natural freq
        int a = swz(n);
        sRe[a] = vr[r]; sIm[a] = vi[r];
    }
    __syncthreads();

#pragma unroll
    for (int r = 0; r < 16; ++r) {
        int n = r * 512 + tid;
        int a = swz(n);
        xfft[base + n] = __floats2half2_rn(sRe[a], sIm[a]);
    }
}

// ---------------- kernel 5: per-frequency complex GEMM (natural order) ----------------
// out_fft[b,i,l] = sum_j x_fft[b,j,l] * kint[i,j,l]
// MAC uses packed f32 (v_pk_fma_f32): acc += {x.x,x.x}*kv + {x.y,x.y}*{-kv.y,kv.x}
#define PB 32
#define IB 16
#define JC 4
__global__ __launch_bounds__(256) void k_gemm(const __half2* __restrict__ xfft,
                                              const float* __restrict__ kmag,
                                              const float* __restrict__ kph,
                                              __hip_bfloat162* __restrict__ outfft) {
    __shared__ v2f xtile[JC][B][PB];    // 16 KB
    __shared__ v2f ktile[JC][IB][PB];   // 16 KB

    int bid = blockIdx.x;
    int ib = bid >> 8;             // 0..3
    int pb = bid & 255;
    int p0 = pb * PB;
    int i0 = ib * IB;
    int tid = threadIdx.x;
    int pl = tid & 31;             // p lane
    int gi = (tid >> 5) & 3;       // i-group: 4 i's each
    int gb = tid >> 7;             // b-group: 8 b's each
    int p = p0 + pl;
    int l = p;                     // natural frequency order

    // interpolation parameters (i0k/i1k wave-uniform within the block)
    float pos = ((float)l + 0.5f) * ((float)KK / (float)L) - 0.5f;
    pos = fminf(fmaxf(pos, 0.0f), (float)(KK - 1));
    int i0k = (int)floorf(pos);
    int i1k = min(i0k + 1, KK - 1);
    float w = pos - (float)i0k;

    v2f acc[8][4];
#pragma unroll
    for (int bb = 0; bb < 8; ++bb)
#pragma unroll
        for (int q = 0; q < 4; ++q) acc[bb][q] = (v2f){0.f, 0.f};

    // prefetch chunk 0 (8 coalesced half2 loads into regs)
    __half2 px[8];
#pragma unroll
    for (int r = 0; r < 8; ++r) {
        int lin = r * 256 + tid;
        int bj = lin >> 5;
        int jj = bj >> 4;
        int bb = bj & 15;
        px[r] = xfft[((size_t)(bb * CIN + jj)) * L + p0 + pl];
    }

    for (int jc = 0; jc < CIN; jc += JC) {
        __syncthreads();
        // commit prefetched x to LDS
#pragma unroll
        for (int r = 0; r < 8; ++r) {
            int lin = r * 256 + tid;
            int bj = lin >> 5;
            int jj = bj >> 4;
            int bb = bj & 15;
            xtile[jj][bb][pl] = (v2f){__low2float(px[r]), __high2float(px[r])};
        }
        // issue next chunk's prefetch (drains during this chunk's MAC)
        if (jc + JC < CIN) {
#pragma unroll
            for (int r = 0; r < 8; ++r) {
                int lin = r * 256 + tid;
                int bj = lin >> 5;
                int jj = bj >> 4;
                int bb = bj & 15;
                px[r] = xfft[((size_t)(bb * CIN + jc + JC + jj)) * L + p0 + pl];
            }
        }
        // kint: wave-uniform broadcast table loads + per-lane native sincos
#pragma unroll
        for (int r = 0; r < 8; ++r) {
            int lin = r * 256 + tid;
            int ij = lin >> 5;
            int jj = ij >> 4;
            int ii = ij & 15;
            int kb = ((i0 + ii) * CIN + jc + jj) * KK;
            float m0 = kmag[kb + i0k], m1 = kmag[kb + i1k];
            float q0 = kph[kb + i0k],  q1 = kph[kb + i1k];
            float mm = m0 + (m1 - m0) * w;
            float ph = q0 + (q1 - q0) * w;
            float sn, cs;
            nsincos(ph, &sn, &cs);
            ktile[jj][ii][pl] = (v2f){mm * cs, mm * sn};
        }
        __syncthreads();

#pragma unroll
        for (int jj = 0; jj < JC; ++jj) {
            v2f kv[4], kvs[4];
#pragma unroll
            for (int q = 0; q < 4; ++q) {
                kv[q] = ktile[jj][gi * 4 + q][pl];
                kvs[q] = (v2f){-kv[q].y, kv[q].x};
            }
#pragma unroll
            for (int bb = 0; bb < 8; ++bb) {
                v2f x = xtile[jj][gb * 8 + bb][pl];
                v2f xx = (v2f){x.x, x.x};
                v2f xy = (v2f){x.y, x.y};
#pragma unroll
                for (int q = 0; q < 4; ++q) {
                    acc[bb][q] = __builtin_elementwise_fma(xx, kv[q], acc[bb][q]);
                    acc[bb][q] = __builtin_elementwise_fma(xy, kvs[q], acc[bb][q]);
                }
            }
        }
    }

#pragma unroll
    for (int q = 0; q < 4; ++q) {
        int i = i0 + gi * 4 + q;
#pragma unroll
        for (int bb = 0; bb < 8; ++bb) {
            int bfull = gb * 8 + bb;
            __hip_bfloat162 o;
            o.x = __float2bfloat16(acc[bb][q].x);
            o.y = __float2bfloat16(acc[bb][q].y);
            outfft[((size_t)(bfull * COUT + i)) * L + p] = o;
        }
    }
}

// ---------------- kernel 6: inverse DIF FFT + bitrev permute + activation ----------------
// input outfft in NATURAL frequency order; DIF inverse (positive twiddles = conj(W)).
__global__ __launch_bounds__(512) void k_ifft(const __hip_bfloat162* __restrict__ outfft,
                                              const float* __restrict__ alpha_,
                                              const float2* __restrict__ Wt,
                                              float* __restrict__ out) {
    __shared__ float sRe[L];
    __shared__ float sIm[L];
    int row = blockIdx.x;          // b*64 + i
    int tid = threadIdx.x;
    float alpha = alpha_[0];
    size_t base = (size_t)row * L;

    for (int rpt = 0; rpt < L / 512; ++rpt) {
        int idx = rpt * 512 + tid;
        __hip_bfloat162 v = outfft[base + idx];
        sRe[idx] = __bfloat162float(v.x);
        sIm[idx] = __bfloat162float(v.y);
    }

    // radix-2 DIF with POSITIVE twiddles (conj of table): natural in -> bitrev out
    for (int s = 0; s < LOG2L; ++s) {
        int lg = LOG2L - 1 - s;
        int len = 1 << lg;
        __syncthreads();
        for (int rpt = 0; rpt < (L / 2) / 512; ++rpt) {
            int t = rpt * 512 + tid;
            int j = t & (len - 1);
            int idx = ((t >> lg) << (lg + 1)) | j;
            float ar = sRe[idx], ai = sIm[idx];
            float br = sRe[idx + len], bi = sIm[idx + len];
            sRe[idx] = ar + br;
            sIm[idx] = ai + bi;
            float dr = ar - br, di = ai - bi;
            float2 tw = Wt[j << s];     // (cos, -sin); need (cos, +sin)
            sRe[idx + len] = dr * tw.x + di * tw.y;
            sIm[idx + len] = di * tw.x - dr * tw.y;
        }
    }
    __syncthreads();

    // bitrev permute to natural order (swizzled scatter)
    float vr[16], vi[16];
#pragma unroll
    for (int r = 0; r < 16; ++r) {
        int idx = r * 512 + tid;
        vr[r] = sRe[idx]; vi[r] = sIm[idx];
    }
    __syncthreads();
#pragma unroll
    for (int r = 0; r < 16; ++r) {
        int idx = r * 512 + tid;
        int n = (int)(__brev((unsigned)idx) >> 19);
        int a = swz(n);
        sRe[a] = vr[r]; sIm[a] = vi[r];
    }
    __syncthreads();

    const float invN = 1.0f / (float)L;
#pragma unroll
    for (int rpt = 0; rpt < L / 512; ++rpt) {
        int n = rpt * 512 + tid;
        float act = sinf(alpha * (float)n);
        out[base + n] = sRe[swz(n)] * act * invN;   // real part only
    }
}

// ---------------- launch ----------------
extern "C" void kernel_launch(void* const* d_in, const int* in_sizes, int n_in,
                              void* d_out, int out_size, void* d_ws, size_t ws_size,
                              hipStream_t stream) {
    const float* xr = (const float*)d_in[0];
    const float* xi = (const float*)d_in[1];
    const float* kr = (const float*)d_in[2];
    const float* ki = (const float*)d_in[3];
    const float* alpha = (const float*)d_in[4];
    float* out = (float*)d_out;

    // ws layout (total ~35.8 MB):
    //   [0, 33.5MB)  out_fft bf16x2 | kmag 1MB | kph 1MB | Wtab 32KB | reduce scratch
    char* ws = (char*)d_ws;
    size_t OFFT_BYTES = (size_t)B * COUT * L * 4;          // 33,554,432
    __hip_bfloat162* outfft = (__hip_bfloat162*)ws;
    float* kmag = (float*)(ws + OFFT_BYTES);
    float* kph  = (float*)(ws + OFFT_BYTES + (size_t)COUT * CIN * KK * 4);
    float2* Wtab = (float2*)(ws + OFFT_BYTES + (size_t)2 * COUT * CIN * KK * 4);
    float* pmin = (float*)(ws + OFFT_BYTES + (size_t)2 * COUT * CIN * KK * 4 + 4096 * 8);
    float* pmax = pmin + 1024;
    float* mmin = pmax + 1024;
    float* mmax = mmin + 16;

    __half2* xfft = (__half2*)d_out;   // exactly out_size*4 bytes; overwritten by k_ifft

    hipLaunchKernelGGL(k_twiddle, dim3(16), dim3(256), 0, stream, Wtab);
    hipLaunchKernelGGL(k_reduce1, dim3(1024), dim3(256), 0, stream, xr, xi, pmin, pmax);
    hipLaunchKernelGGL(k_reduce2, dim3(16), dim3(64), 0, stream, pmin, pmax, mmin, mmax);
    hipLaunchKernelGGL(k_kstats, dim3(4096), dim3(64), 0, stream, kr, ki, kmag, kph);
    hipLaunchKernelGGL(k_fwd, dim3(1024), dim3(512), 0, stream, xr, xi, mmin, mmax, Wtab, xfft);
    hipLaunchKernelGGL(k_gemm, dim3(1024), dim3(256), 0, stream, xfft, kmag, kph, outfft);
    hipLaunchKernelGGL(k_ifft, dim3(1024), dim3(512), 0, stream, outfft, alpha, Wtab, out);
}

// Round 8
// 225.738 us; speedup vs baseline: 1.2814x; 1.2814x over previous
//
#include <hip/hip_runtime.h>
#include <hip/hip_fp16.h>
#include <hip/hip_bf16.h>
#include <math.h>

#define L 8192
#define LOG2L 13
#define B 16
#define CIN 64
#define COUT 64
#define KK 64

#define PI_F 3.14159265358979323846f

typedef float v2f __attribute__((ext_vector_type(2)));

// XOR swizzle for the bit-reversal scatter phase: bijective involution,
// spreads the 32-way bank collision of bitrev-scatter into <=2-way.
__device__ __forceinline__ int swz(int n) { return n ^ ((n >> 8) & 31); }

// native sincos: v_sin_f32/v_cos_f32 take revolutions, reduce with fract first
__device__ __forceinline__ void nsincos(float ang, float* sn, float* cs) {
    float r = ang * 0.15915494309189535f;   // 1/(2*pi)
    r = r - floorf(r);
    *sn = __builtin_amdgcn_sinf(r);
    *cs = __builtin_amdgcn_cosf(r);
}

// ---------------- kernel 1: partial per-batch min/max of |x| ----------------
__global__ __launch_bounds__(256) void k_reduce1(const float* __restrict__ xr,
                                                 const float* __restrict__ xi,
                                                 float* __restrict__ pmin,
                                                 float* __restrict__ pmax) {
    int bid = blockIdx.x;            // 1024 = 16 batches * 64 slices
    int batch = bid >> 6, slice = bid & 63;
    size_t base = (size_t)batch * CIN * L + (size_t)slice * L;
    int tid = threadIdx.x;
    float mn = 3.4e38f, mx = 0.0f;
    for (int r = 0; r < 32; ++r) {
        int idx = r * 256 + tid;
        float a = xr[base + idx], b = xi[base + idx];
        float m = sqrtf(a * a + b * b);
        mn = fminf(mn, m);
        mx = fmaxf(mx, m);
    }
    __shared__ float smn[4], smx[4];
    for (int off = 32; off >= 1; off >>= 1) {
        mn = fminf(mn, __shfl_down(mn, off));
        mx = fmaxf(mx, __shfl_down(mx, off));
    }
    int wave = tid >> 6;
    if ((tid & 63) == 0) { smn[wave] = mn; smx[wave] = mx; }
    __syncthreads();
    if (tid == 0) {
        for (int w = 1; w < 4; ++w) { mn = fminf(mn, smn[w]); mx = fmaxf(mx, smx[w]); }
        pmin[bid] = mn;
        pmax[bid] = mx;
    }
}

// ---------------- kernel 2: final min/max ----------------
__global__ __launch_bounds__(64) void k_reduce2(const float* __restrict__ pmin,
                                                const float* __restrict__ pmax,
                                                float* __restrict__ mmin,
                                                float* __restrict__ mmax) {
    int b = blockIdx.x, t = threadIdx.x;
    float mn = pmin[b * 64 + t], mx = pmax[b * 64 + t];
    for (int off = 32; off >= 1; off >>= 1) {
        mn = fminf(mn, __shfl_down(mn, off));
        mx = fmaxf(mx, __shfl_down(mx, off));
    }
    if (t == 0) { mmin[b] = mn; mmax[b] = mx; }
}

// ---------------- kernel 3: kernel FFT stats (64-pt DFT, mag+phase) ----------------
__global__ __launch_bounds__(64) void k_kstats(const float* __restrict__ kr,
                                               const float* __restrict__ ki,
                                               float* __restrict__ kmag,
                                               float* __restrict__ kph) {
    int row = blockIdx.x;   // o*64 + j  (4096 rows)
    int k = threadIdx.x;    // output frequency 0..63
    __shared__ float sr[64], si[64];
    sr[k] = kr[row * 64 + k];
    si[k] = ki[row * 64 + k];
    __syncthreads();
    float ar = 0.f, ai = 0.f;
    for (int n = 0; n < 64; ++n) {
        int m = (n * k) & 63;                       // exact mod-64 reduction
        float ang = -2.0f * PI_F * (float)m * (1.0f / 64.0f);
        float s, c;
        __sincosf(ang, &s, &c);
        ar += sr[n] * c - si[n] * s;
        ai += sr[n] * s + si[n] * c;
    }
    kmag[row * 64 + k] = sqrtf(ar * ar + ai * ai);
    kph[row * 64 + k] = atan2f(ai, ar);
}

// ---------------- kernel 4: coupling + forward DIF FFT + bitrev permute ----------------
// x_fft written in NATURAL frequency order as half2 into d_out.
// Stages with len<=512 (10 of 13) have j = tid & (len-1) constant across the
// 8 rpt iterations (512 % len == 0), so one native sincos per stage, hoisted.
__global__ __launch_bounds__(512) void k_fwd(const float* __restrict__ xr,
                                             const float* __restrict__ xi,
                                             const float* __restrict__ mmin_,
                                             const float* __restrict__ mmax_,
                                             __half2* __restrict__ xfft) {
    __shared__ float sRe[L];
    __shared__ float sIm[L];
    int row = blockIdx.x;          // b*64 + j
    int b = row >> 6;
    int tid = threadIdx.x;
    float mmin = mmin_[b], mmax = mmax_[b];
    float span = mmax - mmin;
    float invden = 1.0f / (span + 1e-10f);
    size_t base = (size_t)row * L;

    for (int rpt = 0; rpt < L / 512; ++rpt) {
        int idx = rpt * 512 + tid;
        float a = xr[base + idx], c = xi[base + idx];
        float m = sqrtf(a * a + c * c);
        float xn = (m - mmin) * invden;
#pragma unroll
        for (int it = 0; it < 5; ++it) xn = 3.8f * xn * (1.0f - xn);
        float mc = xn * span + mmin;
        float scale = (m > 0.0f) ? (mc / m) : 0.0f;
        sRe[idx] = a * scale;
        sIm[idx] = c * scale;
    }

    // stages 0..2 (len 4096,2048,1024): j varies with rpt -> per-butterfly sincos
    for (int s = 0; s < 3; ++s) {
        int lg = LOG2L - 1 - s;
        int len = 1 << lg;
        float fstep = -PI_F / (float)len;
        __syncthreads();
        for (int rpt = 0; rpt < (L / 2) / 512; ++rpt) {
            int t = rpt * 512 + tid;
            int j = t & (len - 1);
            int idx = ((t >> lg) << (lg + 1)) | j;
            float ar = sRe[idx], ai = sIm[idx];
            float br = sRe[idx + len], bi = sIm[idx + len];
            sRe[idx] = ar + br;
            sIm[idx] = ai + bi;
            float dr = ar - br, di = ai - bi;
            float sn, cs;
            nsincos(fstep * (float)j, &sn, &cs);
            sRe[idx + len] = dr * cs - di * sn;
            sIm[idx + len] = dr * sn + di * cs;
        }
    }
    // stages 3..12 (len<=512): j constant per thread -> one sincos per stage
    for (int s = 3; s < LOG2L; ++s) {
        int lg = LOG2L - 1 - s;
        int len = 1 << lg;
        int j = tid & (len - 1);
        float sn, cs;
        nsincos(-PI_F * (float)j / (float)len, &sn, &cs);
        __syncthreads();
#pragma unroll
        for (int rpt = 0; rpt < (L / 2) / 512; ++rpt) {
            int t = rpt * 512 + tid;
            int idx = ((t >> lg) << (lg + 1)) | j;
            float ar = sRe[idx], ai = sIm[idx];
            float br = sRe[idx + len], bi = sIm[idx + len];
            sRe[idx] = ar + br;
            sIm[idx] = ai + bi;
            float dr = ar - br, di = ai - bi;
            sRe[idx + len] = dr * cs - di * sn;
            sIm[idx + len] = dr * sn + di * cs;
        }
    }
    __syncthreads();

    // in-LDS bit-reversal permute (swizzled scatter; bijective, race-free)
    float vr[16], vi[16];
#pragma unroll
    for (int r = 0; r < 16; ++r) {
        int idx = r * 512 + tid;
        vr[r] = sRe[idx]; vi[r] = sIm[idx];
    }
    __syncthreads();
#pragma unroll
    for (int r = 0; r < 16; ++r) {
        int idx = r * 512 + tid;
        int n = (int)(__brev((unsigned)idx) >> 19);   // target natural freq
        int a = swz(n);
        sRe[a] = vr[r]; sIm[a] = vi[r];
    }
    __syncthreads();

#pragma unroll
    for (int r = 0; r < 16; ++r) {
        int n = r * 512 + tid;
        int a = swz(n);
        xfft[base + n] = __floats2half2_rn(sRe[a], sIm[a]);
    }
}

// ---------------- kernel 5: per-frequency complex GEMM (natural order) ----------------
// out_fft[b,i,l] = sum_j x_fft[b,j,l] * kint[i,j,l]
// MAC uses packed f32 (v_pk_fma_f32): acc += {x.x,x.x}*kv + {x.y,x.y}*{-kv.y,kv.x}
#define PB 32
#define IB 16
#define JC 4
__global__ __launch_bounds__(256) void k_gemm(const __half2* __restrict__ xfft,
                                              const float* __restrict__ kmag,
                                              const float* __restrict__ kph,
                                              __hip_bfloat162* __restrict__ outfft) {
    __shared__ v2f xtile[JC][B][PB];    // 16 KB
    __shared__ v2f ktile[JC][IB][PB];   // 16 KB

    int bid = blockIdx.x;
    int ib = bid >> 8;             // 0..3
    int pb = bid & 255;
    int p0 = pb * PB;
    int i0 = ib * IB;
    int tid = threadIdx.x;
    int pl = tid & 31;             // p lane
    int gi = (tid >> 5) & 3;       // i-group: 4 i's each
    int gb = tid >> 7;             // b-group: 8 b's each
    int p = p0 + pl;
    int l = p;                     // natural frequency order

    // interpolation parameters (i0k/i1k wave-uniform within the block)
    float pos = ((float)l + 0.5f) * ((float)KK / (float)L) - 0.5f;
    pos = fminf(fmaxf(pos, 0.0f), (float)(KK - 1));
    int i0k = (int)floorf(pos);
    int i1k = min(i0k + 1, KK - 1);
    float w = pos - (float)i0k;

    v2f acc[8][4];
#pragma unroll
    for (int bb = 0; bb < 8; ++bb)
#pragma unroll
        for (int q = 0; q < 4; ++q) acc[bb][q] = (v2f){0.f, 0.f};

    // prefetch chunk 0 (8 coalesced half2 loads into regs)
    __half2 px[8];
#pragma unroll
    for (int r = 0; r < 8; ++r) {
        int lin = r * 256 + tid;
        int bj = lin >> 5;
        int jj = bj >> 4;
        int bb = bj & 15;
        px[r] = xfft[((size_t)(bb * CIN + jj)) * L + p0 + pl];
    }

    for (int jc = 0; jc < CIN; jc += JC) {
        __syncthreads();
        // commit prefetched x to LDS
#pragma unroll
        for (int r = 0; r < 8; ++r) {
            int lin = r * 256 + tid;
            int bj = lin >> 5;
            int jj = bj >> 4;
            int bb = bj & 15;
            xtile[jj][bb][pl] = (v2f){__low2float(px[r]), __high2float(px[r])};
        }
        // issue next chunk's prefetch (drains during this chunk's MAC)
        if (jc + JC < CIN) {
#pragma unroll
            for (int r = 0; r < 8; ++r) {
                int lin = r * 256 + tid;
                int bj = lin >> 5;
                int jj = bj >> 4;
                int bb = bj & 15;
                px[r] = xfft[((size_t)(bb * CIN + jc + JC + jj)) * L + p0 + pl];
            }
        }
        // kint: wave-uniform broadcast table loads + per-lane native sincos
#pragma unroll
        for (int r = 0; r < 8; ++r) {
            int lin = r * 256 + tid;
            int ij = lin >> 5;
            int jj = ij >> 4;
            int ii = ij & 15;
            int kb = ((i0 + ii) * CIN + jc + jj) * KK;
            float m0 = kmag[kb + i0k], m1 = kmag[kb + i1k];
            float q0 = kph[kb + i0k],  q1 = kph[kb + i1k];
            float mm = m0 + (m1 - m0) * w;
            float ph = q0 + (q1 - q0) * w;
            float sn, cs;
            nsincos(ph, &sn, &cs);
            ktile[jj][ii][pl] = (v2f){mm * cs, mm * sn};
        }
        __syncthreads();

#pragma unroll
        for (int jj = 0; jj < JC; ++jj) {
            v2f kv[4], kvs[4];
#pragma unroll
            for (int q = 0; q < 4; ++q) {
                kv[q] = ktile[jj][gi * 4 + q][pl];
                kvs[q] = (v2f){-kv[q].y, kv[q].x};
            }
#pragma unroll
            for (int bb = 0; bb < 8; ++bb) {
                v2f x = xtile[jj][gb * 8 + bb][pl];
                v2f xx = (v2f){x.x, x.x};
                v2f xy = (v2f){x.y, x.y};
#pragma unroll
                for (int q = 0; q < 4; ++q) {
                    acc[bb][q] = __builtin_elementwise_fma(xx, kv[q], acc[bb][q]);
                    acc[bb][q] = __builtin_elementwise_fma(xy, kvs[q], acc[bb][q]);
                }
            }
        }
    }

#pragma unroll
    for (int q = 0; q < 4; ++q) {
        int i = i0 + gi * 4 + q;
#pragma unroll
        for (int bb = 0; bb < 8; ++bb) {
            int bfull = gb * 8 + bb;
            __hip_bfloat162 o;
            o.x = __float2bfloat16(acc[bb][q].x);
            o.y = __float2bfloat16(acc[bb][q].y);
            outfft[((size_t)(bfull * COUT + i)) * L + p] = o;
        }
    }
}

// ---------------- kernel 6: inverse DIF FFT + bitrev permute + activation ----------------
// input outfft in NATURAL frequency order; DIF inverse (positive twiddles).
__global__ __launch_bounds__(512) void k_ifft(const __hip_bfloat162* __restrict__ outfft,
                                              const float* __restrict__ alpha_,
                                              float* __restrict__ out) {
    __shared__ float sRe[L];
    __shared__ float sIm[L];
    int row = blockIdx.x;          // b*64 + i
    int tid = threadIdx.x;
    float alpha = alpha_[0];
    size_t base = (size_t)row * L;

    for (int rpt = 0; rpt < L / 512; ++rpt) {
        int idx = rpt * 512 + tid;
        __hip_bfloat162 v = outfft[base + idx];
        sRe[idx] = __bfloat162float(v.x);
        sIm[idx] = __bfloat162float(v.y);
    }

    // stages 0..2: per-butterfly sincos (positive twiddles)
    for (int s = 0; s < 3; ++s) {
        int lg = LOG2L - 1 - s;
        int len = 1 << lg;
        float fstep = PI_F / (float)len;
        __syncthreads();
        for (int rpt = 0; rpt < (L / 2) / 512; ++rpt) {
            int t = rpt * 512 + tid;
            int j = t & (len - 1);
            int idx = ((t >> lg) << (lg + 1)) | j;
            float ar = sRe[idx], ai = sIm[idx];
            float br = sRe[idx + len], bi = sIm[idx + len];
            sRe[idx] = ar + br;
            sIm[idx] = ai + bi;
            float dr = ar - br, di = ai - bi;
            float sn, cs;
            nsincos(fstep * (float)j, &sn, &cs);
            sRe[idx + len] = dr * cs - di * sn;
            sIm[idx + len] = dr * sn + di * cs;
        }
    }
    // stages 3..12: hoisted sincos
    for (int s = 3; s < LOG2L; ++s) {
        int lg = LOG2L - 1 - s;
        int len = 1 << lg;
        int j = tid & (len - 1);
        float sn, cs;
        nsincos(PI_F * (float)j / (float)len, &sn, &cs);
        __syncthreads();
#pragma unroll
        for (int rpt = 0; rpt < (L / 2) / 512; ++rpt) {
            int t = rpt * 512 + tid;
            int idx = ((t >> lg) << (lg + 1)) | j;
            float ar = sRe[idx], ai = sIm[idx];
            float br = sRe[idx + len], bi = sIm[idx + len];
            sRe[idx] = ar + br;
            sIm[idx] = ai + bi;
            float dr = ar - br, di = ai - bi;
            sRe[idx + len] = dr * cs - di * sn;
            sIm[idx + len] = dr * sn + di * cs;
        }
    }
    __syncthreads();

    // bitrev permute to natural order (swizzled scatter)
    float vr[16], vi[16];
#pragma unroll
    for (int r = 0; r < 16; ++r) {
        int idx = r * 512 + tid;
        vr[r] = sRe[idx]; vi[r] = sIm[idx];
    }
    __syncthreads();
#pragma unroll
    for (int r = 0; r < 16; ++r) {
        int idx = r * 512 + tid;
        int n = (int)(__brev((unsigned)idx) >> 19);
        int a = swz(n);
        sRe[a] = vr[r]; sIm[a] = vi[r];
    }
    __syncthreads();

    const float invN = 1.0f / (float)L;
#pragma unroll
    for (int rpt = 0; rpt < L / 512; ++rpt) {
        int n = rpt * 512 + tid;
        float act = sinf(alpha * (float)n);
        out[base + n] = sRe[swz(n)] * act * invN;   // real part only
    }
}

// ---------------- launch ----------------
extern "C" void kernel_launch(void* const* d_in, const int* in_sizes, int n_in,
                              void* d_out, int out_size, void* d_ws, size_t ws_size,
                              hipStream_t stream) {
    const float* xr = (const float*)d_in[0];
    const float* xi = (const float*)d_in[1];
    const float* kr = (const float*)d_in[2];
    const float* ki = (const float*)d_in[3];
    const float* alpha = (const float*)d_in[4];
    float* out = (float*)d_out;

    // ws layout (total ~35.7 MB):
    //   [0, 33.5MB)  out_fft bf16x2 | kmag 1MB | kph 1MB | reduce scratch
    char* ws = (char*)d_ws;
    size_t OFFT_BYTES = (size_t)B * COUT * L * 4;          // 33,554,432
    __hip_bfloat162* outfft = (__hip_bfloat162*)ws;
    float* kmag = (float*)(ws + OFFT_BYTES);
    float* kph  = (float*)(ws + OFFT_BYTES + (size_t)COUT * CIN * KK * 4);
    float* pmin = (float*)(ws + OFFT_BYTES + (size_t)2 * COUT * CIN * KK * 4);
    float* pmax = pmin + 1024;
    float* mmin = pmax + 1024;
    float* mmax = mmin + 16;

    __half2* xfft = (__half2*)d_out;   // exactly out_size*4 bytes; overwritten by k_ifft

    hipLaunchKernelGGL(k_reduce1, dim3(1024), dim3(256), 0, stream, xr, xi, pmin, pmax);
    hipLaunchKernelGGL(k_reduce2, dim3(16), dim3(64), 0, stream, pmin, pmax, mmin, mmax);
    hipLaunchKernelGGL(k_kstats, dim3(4096), dim3(64), 0, stream, kr, ki, kmag, kph);
    hipLaunchKernelGGL(k_fwd, dim3(1024), dim3(512), 0, stream, xr, xi, mmin, mmax, xfft);
    hipLaunchKernelGGL(k_gemm, dim3(1024), dim3(256), 0, stream, xfft, kmag, kph, outfft);
    hipLaunchKernelGGL(k_ifft, dim3(1024), dim3(512), 0, stream, outfft, alpha, out);
}